// Round 5
// baseline (430.391 us; speedup 1.0000x reference)
//
#include <hip/hip_runtime.h>
#include <cstdint>
#include <cstddef>

// TreeLSTM (T=256,B=512,IN=128,M=256,BF=2) — level-scheduled wavefront, R10:
//  - R9 FAILED: B-resident skip was invalid for nCh>4 (buffer j retains chunk
//    16+j's B at tile end, not chunk j's). Fix: skip B ONLY for leaf->leaf
//    same-m0 tile pairs (nCh=4 both: buffers 0-3 <-> chunks 0-3 bijective).
//    Chunks >=4 always stage B. Counted-vmcnt FIFO re-verified for all
//    leaf/full transitions (extra desc loads only over-drain: safe).
//  - NEW: child-bitmask (8 uints in the 32B ws gap after levelStart; computed
//    in prep from batch-0 tree, structurally uniform across batch): epilogue
//    skips hb stores for nodes never referenced as children (all binary nodes
//    here -> level1 saves ~22MB of writes).
//  - Persistent grid-512 + fused prep_conv + depth-3 4-buf + R7 swizzle kept.

#define TT 256
#define BB 512
#define INN 128
#define MM 256
#define BFN 2
#define NLEVEL_LAUNCH 4
#define SL (TT + BFN)
#define KC 32

typedef __attribute__((ext_vector_type(8))) short bf16x8;
typedef __attribute__((ext_vector_type(8))) unsigned short ushort8;
typedef __attribute__((ext_vector_type(16))) float f32x16;

__device__ __forceinline__ unsigned short f2bf(float f) {
  unsigned u = __float_as_uint(f);
  unsigned r = u + 0x7fffu + ((u >> 16) & 1u);  // RTN-even
  return (unsigned short)(r >> 16);
}

__device__ __forceinline__ float sigm_fast(float x) {
  return __builtin_amdgcn_rcpf(1.0f + __expf(-x));
}
__device__ __forceinline__ float tanh_fast(float x) {
  // tanh(x) = 1 - 2/(e^{2x}+1); inf-safe for large |x|
  return 1.0f - 2.0f * __builtin_amdgcn_rcpf(1.0f + __expf(2.0f * x));
}

__device__ __forceinline__ void async16(unsigned short* lds,
                                        const unsigned short* g) {
  __builtin_amdgcn_global_load_lds(
      (const __attribute__((address_space(1))) unsigned int*)g,
      (__attribute__((address_space(3))) unsigned int*)lds, 16, 0, 0);
}

// ---------------------------------------------------------------------------
// Fused prep (stack sim + levels + child mask) + conversion kernel.
// blocks 0..15 : prep_sim (32 threads each; semantics verified R1-R8)
// block  16    : prep_levels (own serial b=0 sim) + child bitmask
// blocks 17+   : conv_all (fp32->bf16 weights+x) + zero-page
// ---------------------------------------------------------------------------
__global__ __launch_bounds__(256) void prep_conv(
    const int* __restrict__ ar, int* __restrict__ cidx, int* __restrict__ root,
    int* __restrict__ order, int* __restrict__ levelStart,
    unsigned* __restrict__ chmask, const float* __restrict__ x,
    const float* __restrict__ Wi, const float* __restrict__ Wo,
    const float* __restrict__ Wu, const float* __restrict__ Ui,
    const float* __restrict__ Uo, const float* __restrict__ Uu,
    unsigned short* __restrict__ wb, unsigned short* __restrict__ xb,
    unsigned short* __restrict__ zb) {
  __shared__ int st[32][SL];                 // prep_sim blocks
  __shared__ int c0s[TT], c1s[TT], lv[TT];   // prep_levels block
  __shared__ int st0[SL];
  const int blk = blockIdx.x;
  const int tid = threadIdx.x;

  if (blk < 16) {
    if (tid >= 32) return;
    const int b = blk * 32 + tid;
    int* s = st[tid];
    for (int i = 0; i < SL; i++) s[i] = 0;
    int sp = BFN - 1;

    auto step = [&](int t, int a) {
      int2 cv;
      {
        const int idx = s[sp];
        cv.x = (a > 0 && idx < t) ? idx : -1;
      }
      {
        int pos = sp - 1;
        if (pos < 0) pos += SL;
        const int idx = s[pos];
        cv.y = (a > 1 && idx < t) ? idx : -1;
      }
      *(int2*)&cidx[((size_t)t * BB + b) * BFN] = cv;
      const int aa = a < 0 ? -a : a;
      sp = sp + 1 - aa;
      if (sp < 0) sp += SL;
      if (sp >= SL) sp -= SL;
      if (a != -1) s[sp] = t;
    };

    int a0 = ar[b], a1 = ar[BB + b], a2 = ar[2 * BB + b], a3 = ar[3 * BB + b];
    for (int t = 0; t < TT; t += 4) {
      int n0 = 0, n1 = 0, n2 = 0, n3 = 0;
      if (t + 4 < TT) {
        n0 = ar[(size_t)(t + 4) * BB + b];
        n1 = ar[(size_t)(t + 5) * BB + b];
        n2 = ar[(size_t)(t + 6) * BB + b];
        n3 = ar[(size_t)(t + 7) * BB + b];
      }
      step(t, a0);
      step(t + 1, a1);
      step(t + 2, a2);
      step(t + 3, a3);
      a0 = n0; a1 = n1; a2 = n2; a3 = n3;
    }
    root[b] = s[sp];
    return;
  }

  if (blk == 16) {
    // serial stack sim for b=0 (exact mirror of step())
    if (tid == 0) {
      for (int i = 0; i < SL; i++) st0[i] = 0;
      int sp = BFN - 1;
      for (int t = 0; t < TT; t++) {
        const int a = ar[(size_t)t * BB];  // batch 0
        const int i0 = st0[sp];
        int p1 = sp - 1;
        if (p1 < 0) p1 += SL;
        const int i1 = st0[p1];
        c0s[t] = (a > 0 && i0 < t) ? i0 : -1;
        c1s[t] = (a > 1 && i1 < t) ? i1 : -1;
        const int aa = a < 0 ? -a : a;
        sp = sp + 1 - aa;
        if (sp < 0) sp += SL;
        if (sp >= SL) sp -= SL;
        if (a != -1) st0[sp] = t;
      }
    }
    if (tid < TT) lv[tid] = 0;
    if (tid < 8) chmask[tid] = 0u;
    __syncthreads();
    // child bitmask (tree structure uniform across batch)
    if (tid < TT) {
      const int c0 = c0s[tid], c1 = c1s[tid];
      if (c0 >= 0) atomicOr(&chmask[c0 >> 5], 1u << (c0 & 31));
      if (c1 >= 0) atomicOr(&chmask[c1 >> 5], 1u << (c1 & 31));
    }
    for (int it = 0; it < NLEVEL_LAUNCH - 1; it++) {
      int nl = 0;
      if (tid < TT) {
        const int c0 = c0s[tid], c1 = c1s[tid];
        if (c0 >= 0) nl = lv[c0] + 1;
        if (c1 >= 0) {
          const int v = lv[c1] + 1;
          if (v > nl) nl = v;
        }
      }
      __syncthreads();
      if (tid < TT) lv[tid] = nl;
      __syncthreads();
    }
    if (tid < TT) {
      const int l = lv[tid];
      int pos = 0;
      for (int j = 0; j < TT; j++) {
        const int lj = lv[j];  // same j across lanes -> LDS broadcast
        pos += (lj < l || (lj == l && j < tid)) ? 1 : 0;
      }
      order[pos] = tid;
    }
    if (tid <= NLEVEL_LAUNCH) {
      int c = 0;
      for (int j = 0; j < TT; j++) c += (lv[j] < tid) ? 1 : 0;
      levelStart[tid] = c;
    }
    return;
  }

  // ---- conv part ----
  const int gid = (blk - 17) * 256 + tid;
  if (gid >= 2158592) {
    if (gid < 2158592 + 64) {
      const ushort8 z = {0, 0, 0, 0, 0, 0, 0, 0};
      *(ushort8*)(zb + (size_t)(gid - 2158592) * 8) = z;
    }
    return;
  }
  const float* src;
  unsigned short* dst;
  size_t off;
  if (gid < 61440) {
    const int g8 = gid * 8;
    dst = wb + g8;
    if (g8 < 98304) {
      const int seg = g8 >> 15;
      off = g8 & 32767;
      src = (seg == 0) ? Wi : (seg == 1) ? Wo : Wu;
    } else {
      const int g2 = g8 - 98304;
      const int seg = g2 >> 17;
      off = g2 & 131071;
      src = (seg == 0) ? Ui : (seg == 1) ? Uo : Uu;
    }
  } else {
    off = ((size_t)(gid - 61440)) * 8;
    src = x;
    dst = xb + off;
  }
  const float4 v0 = *(const float4*)(src + off);
  const float4 v1 = *(const float4*)(src + off + 4);
  ushort8 o;
  o[0] = f2bf(v0.x); o[1] = f2bf(v0.y); o[2] = f2bf(v0.z); o[3] = f2bf(v0.w);
  o[4] = f2bf(v1.x); o[5] = f2bf(v1.y); o[6] = f2bf(v1.z); o[7] = f2bf(v1.w);
  *(ushort8*)dst = o;
}

// ---------------------------------------------------------------------------
// Fused per-level MFMA GEMM + activation.
// R10: persistent grid-512; leaf->leaf same-m0 B-panel skip ONLY (valid:
// nCh=4 both sides -> buffers 0-3 hold exactly chunks 0-3's B). Chunks >=4
// always stage B. Depth-3 4-buf rotation, counted vmcnt, R7 swizzle.
// ---------------------------------------------------------------------------
__global__ __launch_bounds__(256, 4) void level_mfma(
    const unsigned short* __restrict__ xb, float* __restrict__ hf,
    unsigned short* __restrict__ hb, const float* __restrict__ bi,
    const float* __restrict__ bo, const float* __restrict__ bu,
    const unsigned short* __restrict__ wb, const int* __restrict__ cidx,
    const int* __restrict__ order, const int* __restrict__ levelStart,
    const unsigned* __restrict__ chmask, const unsigned short* __restrict__ zb,
    const int level) {
  const int s0 = levelStart[level];
  const int nt = levelStart[level + 1] - s0;
  if (nt <= 0) return;
  const int nTiles = nt * 16;

  const int vbid = ((blockIdx.x & 7) << 6) | (blockIdx.x >> 3);  // XCD-chunked
  const int lo = (int)(((unsigned)vbid * (unsigned)nTiles) >> 9);
  const int hi = (int)(((unsigned)(vbid + 1) * (unsigned)nTiles) >> 9);
  if (lo >= hi) return;

  __shared__ __align__(16) unsigned short AW[4 * 10240];  // exactly 80 KiB

  const int tid = threadIdx.x;
  const int lane = tid & 63;
  const int w = tid >> 6;
  const int ln32 = lane & 31;
  const int lh = lane >> 5;
  const int bw = w & 1;
  const int mw = w >> 1;
  const int lrow = lane & 15;                 // row within 16-row DMA block
  const int skq = (lane >> 4) ^ (lane & 3);   // source granule for slot(lane)

  // LDS offset (shorts) of (row r, k-quad kq) within an A/B region.
  auto loff = [](int r, int kq) {
    return ((r >> 4) << 9) + (((((kq ^ (r & 3)) << 4) | (r & 15))) << 3);
  };

  const int nfull = nt & ~7;
  int m0p = -1, pfp = -1;

  for (int tt = lo; tt < hi; tt++) {
    // tile -> (node, sub): groups of 8 nodes, sub-major within group
    int node, sub;
    if (tt < (nfull << 4)) {
      node = ((tt >> 7) << 3) | (tt & 7);
      sub = (tt & 127) >> 3;
    } else {
      const int r = tt - (nfull << 4);
      const int tg = nt - nfull;  // 1..7
      sub = r / tg;
      node = nfull + (r - sub * tg);
    }
    const int t = order[s0 + node];
    const int b0 = (sub >> 2) << 7;
    const int m0 = (sub & 3) << 6;
    // seg0 B panels resident ONLY after a leaf tile with the same m0
    const bool skip0 = (m0 == m0p) && (pfp == 0);

    // ---- tile prologue -------------------------------------------------
    __syncthreads();  // prev tile fully done with LDS

    // desc loads (older than stages in the vmcnt FIFO -> waits only
    // over-drain; target-chunk draining is never weakened)
    const int2 fa = *(const int2*)&cidx[((size_t)t * BB + b0 + lane) * BFN];
    const int2 fb =
        *(const int2*)&cidx[((size_t)t * BB + b0 + 64 + lane) * BFN];
    const int rA0 = w * 16 + lrow;
    const int rA1 = rA0 + 64;
    const int2 ca = *(const int2*)&cidx[((size_t)t * BB + b0 + rA0) * BFN];
    const int2 cb = *(const int2*)&cidx[((size_t)t * BB + b0 + rA1) * BFN];
    const int cA0 = ca.x, cB0 = ca.y, cA1 = cb.x, cB1 = cb.y;
    const int mcol = m0 + mw * 32 + ln32;
    const float vi = bi[mcol], vo = bo[mcol], vu = bu[mcol];
    const bool wrh = ((chmask[t >> 5] >> (t & 31)) & 1u) != 0u;

    int pf = 0;

    auto stage_chunk = [&](int ci, unsigned short* buf, bool skipB) {
      int seg, k0;
      if (ci < 4) {
        seg = 0;
        k0 = ci * KC;
      } else {
        const int j = ci - 4;
        if ((pf & 1) && j < 8) {
          seg = 1;
          k0 = j * KC;
        } else {
          seg = 2;
          k0 = ((pf & 1) ? j - 8 : j) * KC;
        }
      }
      if (seg == 0) {
#pragma unroll
        for (int u = 0; u < 2; u++) {
          const int j = w + u * 4;
          const int row = j * 16 + lrow;
          async16(buf + j * 512,
                  xb + (((size_t)t * BB + b0 + row) << 7) + k0 + skq * 8);
        }
      } else {
#pragma unroll
        for (int u = 0; u < 2; u++) {
          const int j = w + u * 4;
          const int c = (seg == 1) ? (u ? cA1 : cA0) : (u ? cB1 : cB0);
          const int row = j * 16 + lrow;
          const unsigned short* src =
              (c >= 0)
                  ? hb + (((size_t)c * BB + b0 + row) << 8) + k0 + skq * 8
                  : zb + lane * 8;  // zero page: uniform vmem count
          async16(buf + j * 512, src);
        }
      }
      if (!skipB) {
        const unsigned short* wB = wb + 98304 + (size_t)(seg - 1) * 65536;
#pragma unroll
        for (int u = 0; u < 3; u++) {
          const int jw = w + u * 4;
          const int roww = jw * 16 + lrow;
          const int g3 = roww >> 6;
          const int m = m0 + (roww & 63);
          const unsigned short* base =
              (seg == 0) ? (wb + g3 * 32768 + (size_t)m * INN)
                         : (wB + (size_t)g3 * 131072 + (size_t)m * MM);
          async16(buf + 4096 + jw * 512, base + k0 + skq * 8);
        }
      }
    };

    // prologue: stage chunks 0,1,2 (all seg0; B skipped iff leaf-resident)
    stage_chunk(0, AW, skip0);
    stage_chunk(1, AW + 10240, skip0);
    stage_chunk(2, AW + 2 * 10240, skip0);

    // pf via ballot: identical in every wave (same 128 rows scanned).
    pf = (__any(fa.x >= 0 || fb.x >= 0) ? 1 : 0) |
         (__any(fa.y >= 0 || fb.y >= 0) ? 2 : 0);
    const int nCh = 4 + ((pf & 1) ? 8 : 0) + ((pf & 2) ? 8 : 0);

    // ---- acc init ------------------------------------------------------
    f32x16 aI[2], aO[2], aU[2];
#pragma unroll
    for (int bt = 0; bt < 2; bt++)
#pragma unroll
      for (int r = 0; r < 16; r++) {
        aI[bt][r] = vi;
        aO[bt][r] = vo;
        aU[bt][r] = vu;
      }

    // ---- main chunk loop: 4-buf rotation, 3-deep, counted vmcnt --------
    for (int i = 0; i < nCh; i++) {
      // ops/chunk: 2 if (chunk<4 && skip0) else 5. Chunks >=4 never skip.
      const bool sk = (i < 3) ? skip0 : false;
      if (i + 2 < nCh) {
        if (sk) asm volatile("s_waitcnt vmcnt(4) lgkmcnt(0)" ::: "memory");
        else    asm volatile("s_waitcnt vmcnt(10) lgkmcnt(0)" ::: "memory");
      } else if (i + 1 < nCh) {
        if (sk) asm volatile("s_waitcnt vmcnt(2) lgkmcnt(0)" ::: "memory");
        else    asm volatile("s_waitcnt vmcnt(5) lgkmcnt(0)" ::: "memory");
      } else {
        asm volatile("s_waitcnt vmcnt(0) lgkmcnt(0)" ::: "memory");
      }
      __builtin_amdgcn_s_barrier();
      __builtin_amdgcn_sched_barrier(0);  // nothing crosses above barrier

      if (i + 3 < nCh)
        stage_chunk(i + 3, AW + ((i + 3) & 3) * 10240,
                    ((i + 3) < 4) ? skip0 : false);

      // MFMA over buffer i&3
      {
        const unsigned short* buf = AW + (i & 3) * 10240;
        const int r0 = bw * 64 + ln32;
        const int r1 = r0 + 32;
        const int rw = mw * 32 + ln32;
#pragma unroll
        for (int ks = 0; ks < 2; ks++) {
          const int kq = ks * 2 + lh;
          const bf16x8 a0 = *(const bf16x8*)(buf + loff(r0, kq));
          const bf16x8 a1 = *(const bf16x8*)(buf + loff(r1, kq));
          const bf16x8 bI = *(const bf16x8*)(buf + 4096 + loff(rw, kq));
          const bf16x8 bO = *(const bf16x8*)(buf + 4096 + loff(rw + 64, kq));
          const bf16x8 bU = *(const bf16x8*)(buf + 4096 + loff(rw + 128, kq));
          aI[0] = __builtin_amdgcn_mfma_f32_32x32x16_bf16(a0, bI, aI[0], 0, 0, 0);
          aO[0] = __builtin_amdgcn_mfma_f32_32x32x16_bf16(a0, bO, aO[0], 0, 0, 0);
          aU[0] = __builtin_amdgcn_mfma_f32_32x32x16_bf16(a0, bU, aU[0], 0, 0, 0);
          aI[1] = __builtin_amdgcn_mfma_f32_32x32x16_bf16(a1, bI, aI[1], 0, 0, 0);
          aO[1] = __builtin_amdgcn_mfma_f32_32x32x16_bf16(a1, bO, aO[1], 0, 0, 0);
          aU[1] = __builtin_amdgcn_mfma_f32_32x32x16_bf16(a1, bU, aU[1], 0, 0, 0);
        }
      }
    }

    // ---- epilogue: C/D layout col=lane&31, row=(r&3)+8*(r>>2)+4*lh -----
#pragma unroll
    for (int bt = 0; bt < 2; bt++) {
#pragma unroll
      for (int r = 0; r < 16; r++) {
        const int brow = b0 + bw * 64 + bt * 32 + (r & 3) + 8 * (r >> 2) + 4 * lh;
        const float gi = aI[bt][r];
        const float go = aO[bt][r];
        const float gu = aU[bt][r];
        const float c = sigm_fast(gi) * tanh_fast(gu);
        const float hv = sigm_fast(go) * tanh_fast(c);
        hf[((size_t)t * BB + brow) * MM + mcol] = hv;
        if (wrh) hb[(((size_t)t * BB + brow) << 8) + mcol] = f2bf(hv);
      }
    }

    m0p = m0;
    pfp = pf;
  }
}

// ---------------------------------------------------------------------------
// Root gather: out[b][m] = h[root[b]][b][m]
// ---------------------------------------------------------------------------
__global__ __launch_bounds__(256) void root_gather(const float* __restrict__ h,
                                                   const int* __restrict__ root,
                                                   float* __restrict__ out) {
  const int idx = blockIdx.x * 256 + threadIdx.x;
  const int b = idx >> 8;
  const int m = idx & 255;
  out[idx] = h[((size_t)root[b] * BB + b) * MM + m];
}

extern "C" void kernel_launch(void* const* d_in, const int* in_sizes, int n_in,
                              void* d_out, int out_size, void* d_ws,
                              size_t ws_size, hipStream_t stream) {
  const float* x = (const float*)d_in[0];
  const int* ar = (const int*)d_in[1];
  const float* Wi = (const float*)d_in[2];
  const float* bi = (const float*)d_in[3];
  const float* Wo = (const float*)d_in[4];
  const float* bo = (const float*)d_in[5];
  const float* Wu = (const float*)d_in[6];
  const float* bu = (const float*)d_in[7];
  // d_in[8]=Wf, d_in[9]=bf_b, d_in[13]=Uf: dead in the reference (fc_sum bug)
  const float* Ui = (const float*)d_in[10];
  const float* Uo = (const float*)d_in[11];
  const float* Uu = (const float*)d_in[12];

  float* out = (float*)d_out;
  float* hf = out + (size_t)BB * MM;  // memory[:, :, :M] region, [T][B][M]

  // ws layout identical to R6-R8 + chmask in the 32B gap after levelStart:
  int* cidx = (int*)d_ws;                    // 262144 ints
  int* root = cidx + (size_t)TT * BB * BFN;  // 512
  int* order = root + BB;                    // 256
  int* levelStart = order + TT;              // 8
  unsigned* chmask = (unsigned*)(levelStart + 8);  // 8 uints (256 bits)
  unsigned short* wb = (unsigned short*)((char*)d_ws + 1051712);   // 491520 sh
  unsigned short* xb = (unsigned short*)((char*)d_ws + 2034752);   // 16.7M sh
  unsigned short* hb = (unsigned short*)((char*)d_ws + 35589184);  // 33.5M sh
  unsigned short* zb = (unsigned short*)((char*)d_ws + 102698048); // 512 sh

  prep_conv<<<8450, 256, 0, stream>>>(ar, cidx, root, order, levelStart,
                                      chmask, x, Wi, Wo, Wu, Ui, Uo, Uu, wb,
                                      xb, zb);
  for (int lev = 0; lev < NLEVEL_LAUNCH; lev++) {
    level_mfma<<<512, 256, 0, stream>>>(xb, hf, hb, bi, bo, bu, wb, cidx,
                                        order, levelStart, chmask, zb, lev);
  }
  root_gather<<<(BB * MM) / 256, 256, 0, stream>>>(hf, root, out);
}